// Round 2
// baseline (409.535 us; speedup 1.0000x reference)
//
#include <hip/hip_runtime.h>
#include <hip/hip_bf16.h>

// ---------------------------------------------------------------------------
// GlobalIntrinsicLinear: Fastfood update + GEMM
//   LL = 1<<20, DD = 1024*768, OUT=1024, IN=768, M = 8*2048 = 16384
// Inputs: x(8,2048,768) f32, theta(2048) f32, W_0(1024,768) f32, b(1024) f32,
//         BB(LL) f32, GG(LL) f32, Pi(LL) int32 (harness converts int64->int32)
// Output: (8,2048,1024) f32
// ---------------------------------------------------------------------------

#define LL (1 << 20)
#define DD (1024 * 768)
#define OUTF 1024
#define INF 768
#define MROWS 16384

typedef __attribute__((ext_vector_type(8))) short s16x8;
typedef __attribute__((ext_vector_type(4))) float f32x4;

__device__ __forceinline__ unsigned short f2bf(float f) {
    union { float f; unsigned u; } v; v.f = f;
    unsigned r = v.u + 0x7FFF + ((v.u >> 16) & 1);   // RNE
    return (unsigned short)(r >> 16);
}

// ---------------------------------------------------------------------------
// K0: FWHT-1024 of the two nonzero rows of BB*theta_pad; also zero the S accum.
// One block, 256 threads. Writes r01[2048] = {r0, r1}.
// Math: full FWHT_{2^20} of a vector nonzero only at q<2048 collapses to
//   v1[p] = r0[p&1023] + (-1)^{bit10(p)} * r1[p&1023]
// where r0/r1 = FWHT_1024 of rows 0/1. (Hadamard factorizes over index bits.)
// ---------------------------------------------------------------------------
__global__ void k0_fwht2(const float* __restrict__ BB, const float* __restrict__ theta,
                         float* __restrict__ r01, float* __restrict__ S) {
    __shared__ float s[2048];
    const int tid = threadIdx.x;
    if (tid == 0) *S = 0.0f;
    for (int j = tid; j < 2048; j += 256) s[j] = BB[j] * theta[j];
    for (int h = 1; h < 1024; h <<= 1) {
        __syncthreads();
        for (int w = tid; w < 1024; w += 256) {
            int row = w >> 9;            // 0..1
            int b   = w & 511;           // butterfly id
            int bh  = b & (h - 1);
            int i   = ((b - bh) << 1) + bh + row * 1024;
            float a = s[i], c = s[i + h];
            s[i] = a + c; s[i + h] = a - c;
        }
    }
    __syncthreads();
    for (int j = tid; j < 2048; j += 256) r01[j] = s[j];
}

// ---------------------------------------------------------------------------
// K2: t[i] = (r0[lo] + sgn*r1[lo]) * GG[i] with p=Pi[i]; fused sum(GG^2).
// Pi arrives as int32 from the harness (int64 inputs are narrowed).
// ---------------------------------------------------------------------------
__global__ void k2_gather(const int* __restrict__ Pi, const float* __restrict__ GG,
                          const float* __restrict__ r01, float* __restrict__ T,
                          float* __restrict__ S) {
    const int i = blockIdx.x * 256 + threadIdx.x;
    const int p = Pi[i];
    const int lo = p & 1023;
    const float sgn = ((p >> 10) & 1) ? -1.0f : 1.0f;
    const float g = GG[i];
    T[i] = (r01[lo] + sgn * r01[1024 + lo]) * g;
    float g2 = g * g;
    #pragma unroll
    for (int o = 32; o > 0; o >>= 1) g2 += __shfl_down(g2, o, 64);
    if ((threadIdx.x & 63) == 0) atomicAdd(S, g2);
}

// ---------------------------------------------------------------------------
// K3: FWHT-1024 along the low-10 bits (one row per block), in place.
// ---------------------------------------------------------------------------
__global__ void k3_fwht_lo(float* __restrict__ T) {
    __shared__ float s[1024];
    const int tid = threadIdx.x;
    const int row = blockIdx.x;
    float4* T4 = (float4*)T;
    float4 v = T4[row * 256 + tid];
    s[tid * 4 + 0] = v.x; s[tid * 4 + 1] = v.y; s[tid * 4 + 2] = v.z; s[tid * 4 + 3] = v.w;
    for (int h = 1; h < 1024; h <<= 1) {
        __syncthreads();
        for (int w = tid; w < 512; w += 256) {
            int bh = w & (h - 1);
            int i  = ((w - bh) << 1) + bh;
            float a = s[i], c = s[i + h];
            s[i] = a + c; s[i + h] = a - c;
        }
    }
    __syncthreads();
    v.x = s[tid * 4 + 0]; v.y = s[tid * 4 + 1]; v.z = s[tid * 4 + 2]; v.w = s[tid * 4 + 3];
    T4[row * 256 + tid] = v;
}

// ---------------------------------------------------------------------------
// K4: FWHT-1024 along the high-10 bits. 128 blocks x 8 lo-columns each.
// LDS tile [8][1025] = 32.8 KB (pad +1 -> conflict-free butterflies along hi).
// ---------------------------------------------------------------------------
__global__ void k4_fwht_hi(float* __restrict__ T) {
    __shared__ float s[8 * 1025];
    const int tid = threadIdx.x;
    const int lo0 = blockIdx.x * 8;
    float4* T4 = (float4*)T;
    const int hio = tid >> 1;     // 0..127
    const int q   = tid & 1;      // which float4 of the 8 columns
    for (int hb = 0; hb < 8; hb++) {
        int hi = hb * 128 + hio;
        float4 v = T4[hi * 256 + (lo0 >> 2) + q];
        s[(4 * q + 0) * 1025 + hi] = v.x;
        s[(4 * q + 1) * 1025 + hi] = v.y;
        s[(4 * q + 2) * 1025 + hi] = v.z;
        s[(4 * q + 3) * 1025 + hi] = v.w;
    }
    for (int h = 1; h < 1024; h <<= 1) {
        __syncthreads();
        for (int w = tid; w < 8 * 512; w += 256) {
            int col = w >> 9;
            int b   = w & 511;
            int bh  = b & (h - 1);
            int i   = ((b - bh) << 1) + bh;
            float* p = s + col * 1025;
            float a = p[i], c = p[i + h];
            p[i] = a + c; p[i + h] = a - c;
        }
    }
    __syncthreads();
    for (int hb = 0; hb < 8; hb++) {
        int hi = hb * 128 + hio;
        float4 v;
        v.x = s[(4 * q + 0) * 1025 + hi];
        v.y = s[(4 * q + 1) * 1025 + hi];
        v.z = s[(4 * q + 2) * 1025 + hi];
        v.w = s[(4 * q + 3) * 1025 + hi];
        T4[hi * 256 + (lo0 >> 2) + q] = v;
    }
}

// ---------------------------------------------------------------------------
// K5: W_eff = bf16(W_0 + v[:DD] * rsqrt(S*DD))   (row-major 1024x768)
// update = v / (sqrt(LL*S) * sqrt(DD/LL)) = v / sqrt(S*DD)
// ---------------------------------------------------------------------------
__global__ void k5_weff(const float* __restrict__ T, const float* __restrict__ W0,
                        const float* __restrict__ S, ushort* __restrict__ WB) {
    const int i = blockIdx.x * 256 + threadIdx.x;     // float4 index, DD/4 total
    const float scale = rsqrtf(*S * (float)DD);
    float4 v = ((const float4*)T)[i];
    float4 w = ((const float4*)W0)[i];
    ushort4 o;
    o.x = f2bf(w.x + v.x * scale);
    o.y = f2bf(w.y + v.y * scale);
    o.z = f2bf(w.z + v.z * scale);
    o.w = f2bf(w.w + v.w * scale);
    ((ushort4*)WB)[i] = o;
}

// ---------------------------------------------------------------------------
// K6: x (f32) -> bf16
// ---------------------------------------------------------------------------
__global__ void k6_xcast(const float* __restrict__ X, ushort* __restrict__ XB) {
    const int i = blockIdx.x * 256 + threadIdx.x;     // float4 index
    float4 v = ((const float4*)X)[i];
    ushort4 o;
    o.x = f2bf(v.x); o.y = f2bf(v.y); o.z = f2bf(v.z); o.w = f2bf(v.w);
    ((ushort4*)XB)[i] = o;
}

// ---------------------------------------------------------------------------
// K7: GEMM  C[m][n] = sum_k A[m][k]*B[n][k] + bias[n]
// A: MROWS x 768 bf16, B: 1024 x 768 bf16 (W_eff), C: f32.
// 128x128 tile, BK=32, 4 waves (2x2), each wave 4x4 MFMA 16x16x32 tiles.
// global_load_lds width=16 staging (contiguous lane order, no padding).
// ---------------------------------------------------------------------------
#define BM 128
#define BN 128
#define BK 32

__global__ __launch_bounds__(256)
void k7_gemm(const ushort* __restrict__ A, const ushort* __restrict__ B,
             const float* __restrict__ bias, float* __restrict__ C) {
    __shared__ ushort As[BM * BK];   // 8 KB
    __shared__ ushort Bs[BN * BK];   // 8 KB
    const int tid  = threadIdx.x;
    const int lane = tid & 63;
    const int wave = tid >> 6;
    const int m0 = blockIdx.y * BM;
    const int n0 = blockIdx.x * BN;
    const int wm = (wave & 1) * 64;
    const int wn = (wave >> 1) * 64;

    const int fr_row = lane & 15;
    const int fr_k   = (lane >> 4) * 8;

    f32x4 acc[4][4];
    #pragma unroll
    for (int i = 0; i < 4; i++)
        #pragma unroll
        for (int j = 0; j < 4; j++) acc[i][j] = (f32x4)(0.0f);

    const int s0 = wave * 64 + lane;       // == tid, segment id issue 0
    const int s1 = s0 + 256;               // segment id issue 1

    for (int kt = 0; kt < INF; kt += BK) {
        // --- stage A and B tiles: 512 segments x 16B each, 2 issues ---
        {
            const ushort* ga0 = A + (size_t)(m0 + (s0 >> 2)) * INF + kt + (s0 & 3) * 8;
            const ushort* gb0 = B + (size_t)(n0 + (s0 >> 2)) * INF + kt + (s0 & 3) * 8;
            const ushort* ga1 = A + (size_t)(m0 + (s1 >> 2)) * INF + kt + (s1 & 3) * 8;
            const ushort* gb1 = B + (size_t)(n0 + (s1 >> 2)) * INF + kt + (s1 & 3) * 8;
            __builtin_amdgcn_global_load_lds(
                (const __attribute__((address_space(1))) void*)ga0,
                (__attribute__((address_space(3))) void*)&As[wave * 512], 16, 0, 0);
            __builtin_amdgcn_global_load_lds(
                (const __attribute__((address_space(1))) void*)gb0,
                (__attribute__((address_space(3))) void*)&Bs[wave * 512], 16, 0, 0);
            __builtin_amdgcn_global_load_lds(
                (const __attribute__((address_space(1))) void*)ga1,
                (__attribute__((address_space(3))) void*)&As[2048 + wave * 512], 16, 0, 0);
            __builtin_amdgcn_global_load_lds(
                (const __attribute__((address_space(1))) void*)gb1,
                (__attribute__((address_space(3))) void*)&Bs[2048 + wave * 512], 16, 0, 0);
        }
        __syncthreads();

        // --- fragments + MFMA ---
        s16x8 af[4], bf[4];
        #pragma unroll
        for (int mi = 0; mi < 4; mi++)
            af[mi] = *(const s16x8*)&As[(wm + mi * 16 + fr_row) * BK + fr_k];
        #pragma unroll
        for (int ni = 0; ni < 4; ni++)
            bf[ni] = *(const s16x8*)&Bs[(wn + ni * 16 + fr_row) * BK + fr_k];
        #pragma unroll
        for (int mi = 0; mi < 4; mi++)
            #pragma unroll
            for (int ni = 0; ni < 4; ni++)
                acc[mi][ni] = __builtin_amdgcn_mfma_f32_16x16x32_bf16(
                    af[mi], bf[ni], acc[mi][ni], 0, 0, 0);
        __syncthreads();
    }

    // --- epilogue: C/D layout col=lane&15, row=(lane>>4)*4+reg ---
    const int crow = (lane >> 4) * 4;
    const int ccol = lane & 15;
    #pragma unroll
    for (int ni = 0; ni < 4; ni++) {
        const int n = n0 + wn + ni * 16 + ccol;
        const float bv = bias[n];
        #pragma unroll
        for (int mi = 0; mi < 4; mi++) {
            const int mbase = m0 + wm + mi * 16 + crow;
            #pragma unroll
            for (int r = 0; r < 4; r++)
                C[(size_t)(mbase + r) * OUTF + n] = acc[mi][ni][r] + bv;
        }
    }
}

// ---------------------------------------------------------------------------
extern "C" void kernel_launch(void* const* d_in, const int* in_sizes, int n_in,
                              void* d_out, int out_size, void* d_ws, size_t ws_size,
                              hipStream_t stream) {
    (void)in_sizes; (void)n_in; (void)out_size; (void)ws_size;
    const float* x     = (const float*)d_in[0];
    const float* theta = (const float*)d_in[1];
    const float* W0    = (const float*)d_in[2];
    const float* bias  = (const float*)d_in[3];
    const float* BB    = (const float*)d_in[4];
    const float* GG    = (const float*)d_in[5];
    const int*   Pi    = (const int*)d_in[6];      // int64 inputs arrive as int32
    float* out = (float*)d_out;

    char* ws = (char*)d_ws;
    ushort* XB  = (ushort*)ws;                       // 16384*768 bf16 = 25165824 B
    float*  T   = (float*)(ws + 25165824);           // LL f32 = 4194304 B
    ushort* WB  = (ushort*)(ws + 29360128);          // 1024*768 bf16 = 1572864 B
    float*  R01 = (float*)(ws + 30932992);           // 2048 f32
    float*  S   = (float*)(ws + 30941184);           // 1 f32

    k0_fwht2 <<<1,    256, 0, stream>>>(BB, theta, R01, S);
    k2_gather<<<LL/256, 256, 0, stream>>>(Pi, GG, R01, T, S);
    k3_fwht_lo<<<1024, 256, 0, stream>>>(T);
    k4_fwht_hi<<<128, 256, 0, stream>>>(T);
    k5_weff  <<<DD/1024, 256, 0, stream>>>(T, W0, S, WB);
    k6_xcast <<<(MROWS*INF)/1024, 256, 0, stream>>>(x, XB);
    k7_gemm  <<<dim3(OUTF/BN, MROWS/BM), 256, 0, stream>>>(XB, WB, bias, out);
}

// Round 3
// 203.714 us; speedup vs baseline: 2.0103x; 2.0103x over previous
//
#include <hip/hip_runtime.h>
#include <hip/hip_bf16.h>

// ---------------------------------------------------------------------------
// GlobalIntrinsicLinear: Fastfood update + GEMM
//   LL = 1<<20, DD = 1024*768, OUT=1024, IN=768, M = 8*2048 = 16384
// Inputs: x(8,2048,768) f32, theta(2048) f32, W_0(1024,768) f32, b(1024) f32,
//         BB(LL) f32, GG(LL) f32, Pi(LL) int32 (harness narrows int64)
// Output: (8,2048,1024) f32
//
// R3: removed single-address atomicAdd hotspot (was 211 us serialized);
//     sum(GG^2) is now a 2-stage reduction; gather fused into lo-FWHT.
// ---------------------------------------------------------------------------

#define LL (1 << 20)
#define DD (1024 * 768)
#define OUTF 1024
#define INF 768
#define MROWS 16384

typedef __attribute__((ext_vector_type(8))) short s16x8;
typedef __attribute__((ext_vector_type(4))) float f32x4;

__device__ __forceinline__ unsigned short f2bf(float f) {
    union { float f; unsigned u; } v; v.f = f;
    unsigned r = v.u + 0x7FFF + ((v.u >> 16) & 1);   // RNE
    return (unsigned short)(r >> 16);
}

// ---------------------------------------------------------------------------
// K1: partial sums of GG^2. 256 blocks x 256 threads, grid-stride float4.
// No atomics — per-block partial to partial[block].
// ---------------------------------------------------------------------------
__global__ void k1_sumsq(const float* __restrict__ GG, float* __restrict__ partial) {
    const int tid = threadIdx.x;
    const float4* G4 = (const float4*)GG;
    float s = 0.0f;
    for (int i = blockIdx.x * 256 + tid; i < LL / 4; i += 256 * 256) {
        float4 g = G4[i];
        s += g.x * g.x + g.y * g.y + g.z * g.z + g.w * g.w;
    }
    #pragma unroll
    for (int o = 32; o > 0; o >>= 1) s += __shfl_down(s, o, 64);
    __shared__ float ws[4];
    if ((tid & 63) == 0) ws[tid >> 6] = s;
    __syncthreads();
    if (tid == 0) partial[blockIdx.x] = ws[0] + ws[1] + ws[2] + ws[3];
}

// ---------------------------------------------------------------------------
// K0: reduce partials -> S, then FWHT-1024 of the two nonzero rows of
// BB*theta_pad. One block, 256 threads. Writes r01[2048] = {r0, r1}.
// Math: FWHT_{2^20} of a vector nonzero only at q<2048 collapses to
//   v1[p] = r0[p&1023] + (-1)^{bit10(p)} * r1[p&1023].
// ---------------------------------------------------------------------------
__global__ void k0_fwht2(const float* __restrict__ BB, const float* __restrict__ theta,
                         const float* __restrict__ partial,
                         float* __restrict__ r01, float* __restrict__ S) {
    __shared__ float s[2048];
    __shared__ float red[256];
    const int tid = threadIdx.x;
    // reduce the 256 partials
    float p = partial[tid];
    red[tid] = p;
    __syncthreads();
    #pragma unroll
    for (int o = 128; o > 0; o >>= 1) {
        if (tid < o) red[tid] += red[tid + o];
        __syncthreads();
    }
    if (tid == 0) *S = red[0];
    // FWHT of the two nonzero 1024-rows
    for (int j = tid; j < 2048; j += 256) s[j] = BB[j] * theta[j];
    for (int h = 1; h < 1024; h <<= 1) {
        __syncthreads();
        for (int w = tid; w < 1024; w += 256) {
            int row = w >> 9;
            int b   = w & 511;
            int bh  = b & (h - 1);
            int i   = ((b - bh) << 1) + bh + row * 1024;
            float a = s[i], c = s[i + h];
            s[i] = a + c; s[i + h] = a - c;
        }
    }
    __syncthreads();
    for (int j = tid; j < 2048; j += 256) r01[j] = s[j];
}

// ---------------------------------------------------------------------------
// K3: fused gather + FWHT-1024 along low-10 bits. One row (hi index) per
// block. t[i] = (r0[lo] + sgn*r1[lo]) * GG[i], p = Pi[i], then in-LDS FWHT.
// r01 staged in LDS to keep the random lo-gather off L1.
// ---------------------------------------------------------------------------
__global__ void k3_gather_fwht_lo(const int* __restrict__ Pi, const float* __restrict__ GG,
                                  const float* __restrict__ r01, float* __restrict__ T) {
    __shared__ float s[1024];
    __shared__ float r01s[2048];
    const int tid = threadIdx.x;
    const int row = blockIdx.x;
    for (int j = tid; j < 2048; j += 256) r01s[j] = r01[j];
    const int4  pv = ((const int4*)Pi)[row * 256 + tid];
    const float4 gv = ((const float4*)GG)[row * 256 + tid];
    __syncthreads();
    {
        int p; float g, v;
        p = pv.x; g = gv.x;
        v = (r01s[p & 1023] + (((p >> 10) & 1) ? -1.0f : 1.0f) * r01s[1024 + (p & 1023)]) * g;
        s[tid * 4 + 0] = v;
        p = pv.y; g = gv.y;
        v = (r01s[p & 1023] + (((p >> 10) & 1) ? -1.0f : 1.0f) * r01s[1024 + (p & 1023)]) * g;
        s[tid * 4 + 1] = v;
        p = pv.z; g = gv.z;
        v = (r01s[p & 1023] + (((p >> 10) & 1) ? -1.0f : 1.0f) * r01s[1024 + (p & 1023)]) * g;
        s[tid * 4 + 2] = v;
        p = pv.w; g = gv.w;
        v = (r01s[p & 1023] + (((p >> 10) & 1) ? -1.0f : 1.0f) * r01s[1024 + (p & 1023)]) * g;
        s[tid * 4 + 3] = v;
    }
    for (int h = 1; h < 1024; h <<= 1) {
        __syncthreads();
        for (int w = tid; w < 512; w += 256) {
            int bh = w & (h - 1);
            int i  = ((w - bh) << 1) + bh;
            float a = s[i], c = s[i + h];
            s[i] = a + c; s[i + h] = a - c;
        }
    }
    __syncthreads();
    float4 v;
    v.x = s[tid * 4 + 0]; v.y = s[tid * 4 + 1]; v.z = s[tid * 4 + 2]; v.w = s[tid * 4 + 3];
    ((float4*)T)[row * 256 + tid] = v;
}

// ---------------------------------------------------------------------------
// K4: FWHT-1024 along the high-10 bits. 128 blocks x 8 lo-columns each.
// LDS tile [8][1025] = 32.8 KB (pad +1 -> conflict-free butterflies).
// ---------------------------------------------------------------------------
__global__ void k4_fwht_hi(float* __restrict__ T) {
    __shared__ float s[8 * 1025];
    const int tid = threadIdx.x;
    const int lo0 = blockIdx.x * 8;
    float4* T4 = (float4*)T;
    const int hio = tid >> 1;     // 0..127
    const int q   = tid & 1;      // which float4 of the 8 columns
    for (int hb = 0; hb < 8; hb++) {
        int hi = hb * 128 + hio;
        float4 v = T4[hi * 256 + (lo0 >> 2) + q];
        s[(4 * q + 0) * 1025 + hi] = v.x;
        s[(4 * q + 1) * 1025 + hi] = v.y;
        s[(4 * q + 2) * 1025 + hi] = v.z;
        s[(4 * q + 3) * 1025 + hi] = v.w;
    }
    for (int h = 1; h < 1024; h <<= 1) {
        __syncthreads();
        for (int w = tid; w < 8 * 512; w += 256) {
            int col = w >> 9;
            int b   = w & 511;
            int bh  = b & (h - 1);
            int i   = ((b - bh) << 1) + bh;
            float* p = s + col * 1025;
            float a = p[i], c = p[i + h];
            p[i] = a + c; p[i + h] = a - c;
        }
    }
    __syncthreads();
    for (int hb = 0; hb < 8; hb++) {
        int hi = hb * 128 + hio;
        float4 v;
        v.x = s[(4 * q + 0) * 1025 + hi];
        v.y = s[(4 * q + 1) * 1025 + hi];
        v.z = s[(4 * q + 2) * 1025 + hi];
        v.w = s[(4 * q + 3) * 1025 + hi];
        T4[hi * 256 + (lo0 >> 2) + q] = v;
    }
}

// ---------------------------------------------------------------------------
// K5: W_eff = bf16(W_0 + v[:DD] * rsqrt(S*DD))   (row-major 1024x768)
// update = v / (sqrt(LL*S) * sqrt(DD/LL)) = v / sqrt(S*DD)
// ---------------------------------------------------------------------------
__global__ void k5_weff(const float* __restrict__ T, const float* __restrict__ W0,
                        const float* __restrict__ S, ushort* __restrict__ WB) {
    const int i = blockIdx.x * 256 + threadIdx.x;     // float4 index, DD/4 total
    const float scale = rsqrtf(*S * (float)DD);
    float4 v = ((const float4*)T)[i];
    float4 w = ((const float4*)W0)[i];
    ushort4 o;
    o.x = f2bf(w.x + v.x * scale);
    o.y = f2bf(w.y + v.y * scale);
    o.z = f2bf(w.z + v.z * scale);
    o.w = f2bf(w.w + v.w * scale);
    ((ushort4*)WB)[i] = o;
}

// ---------------------------------------------------------------------------
// K6: x (f32) -> bf16
// ---------------------------------------------------------------------------
__global__ void k6_xcast(const float* __restrict__ X, ushort* __restrict__ XB) {
    const int i = blockIdx.x * 256 + threadIdx.x;     // float4 index
    float4 v = ((const float4*)X)[i];
    ushort4 o;
    o.x = f2bf(v.x); o.y = f2bf(v.y); o.z = f2bf(v.z); o.w = f2bf(v.w);
    ((ushort4*)XB)[i] = o;
}

// ---------------------------------------------------------------------------
// K7: GEMM  C[m][n] = sum_k A[m][k]*B[n][k] + bias[n]
// A: MROWS x 768 bf16, B: 1024 x 768 bf16 (W_eff), C: f32.
// 128x128 tile, BK=32, 4 waves (2x2), each wave 4x4 MFMA 16x16x32 tiles.
// global_load_lds width=16 staging (contiguous lane order, no padding).
// ---------------------------------------------------------------------------
#define BM 128
#define BN 128
#define BK 32

__global__ __launch_bounds__(256)
void k7_gemm(const ushort* __restrict__ A, const ushort* __restrict__ B,
             const float* __restrict__ bias, float* __restrict__ C) {
    __shared__ ushort As[BM * BK];   // 8 KB
    __shared__ ushort Bs[BN * BK];   // 8 KB
    const int tid  = threadIdx.x;
    const int lane = tid & 63;
    const int wave = tid >> 6;
    const int m0 = blockIdx.y * BM;
    const int n0 = blockIdx.x * BN;
    const int wm = (wave & 1) * 64;
    const int wn = (wave >> 1) * 64;

    const int fr_row = lane & 15;
    const int fr_k   = (lane >> 4) * 8;

    f32x4 acc[4][4];
    #pragma unroll
    for (int i = 0; i < 4; i++)
        #pragma unroll
        for (int j = 0; j < 4; j++) acc[i][j] = (f32x4)(0.0f);

    const int s0 = wave * 64 + lane;
    const int s1 = s0 + 256;

    for (int kt = 0; kt < INF; kt += BK) {
        {
            const ushort* ga0 = A + (size_t)(m0 + (s0 >> 2)) * INF + kt + (s0 & 3) * 8;
            const ushort* gb0 = B + (size_t)(n0 + (s0 >> 2)) * INF + kt + (s0 & 3) * 8;
            const ushort* ga1 = A + (size_t)(m0 + (s1 >> 2)) * INF + kt + (s1 & 3) * 8;
            const ushort* gb1 = B + (size_t)(n0 + (s1 >> 2)) * INF + kt + (s1 & 3) * 8;
            __builtin_amdgcn_global_load_lds(
                (const __attribute__((address_space(1))) void*)ga0,
                (__attribute__((address_space(3))) void*)&As[wave * 512], 16, 0, 0);
            __builtin_amdgcn_global_load_lds(
                (const __attribute__((address_space(1))) void*)gb0,
                (__attribute__((address_space(3))) void*)&Bs[wave * 512], 16, 0, 0);
            __builtin_amdgcn_global_load_lds(
                (const __attribute__((address_space(1))) void*)ga1,
                (__attribute__((address_space(3))) void*)&As[2048 + wave * 512], 16, 0, 0);
            __builtin_amdgcn_global_load_lds(
                (const __attribute__((address_space(1))) void*)gb1,
                (__attribute__((address_space(3))) void*)&Bs[2048 + wave * 512], 16, 0, 0);
        }
        __syncthreads();

        s16x8 af[4], bf[4];
        #pragma unroll
        for (int mi = 0; mi < 4; mi++)
            af[mi] = *(const s16x8*)&As[(wm + mi * 16 + fr_row) * BK + fr_k];
        #pragma unroll
        for (int ni = 0; ni < 4; ni++)
            bf[ni] = *(const s16x8*)&Bs[(wn + ni * 16 + fr_row) * BK + fr_k];
        #pragma unroll
        for (int mi = 0; mi < 4; mi++)
            #pragma unroll
            for (int ni = 0; ni < 4; ni++)
                acc[mi][ni] = __builtin_amdgcn_mfma_f32_16x16x32_bf16(
                    af[mi], bf[ni], acc[mi][ni], 0, 0, 0);
        __syncthreads();
    }

    const int crow = (lane >> 4) * 4;
    const int ccol = lane & 15;
    #pragma unroll
    for (int ni = 0; ni < 4; ni++) {
        const int n = n0 + wn + ni * 16 + ccol;
        const float bv = bias[n];
        #pragma unroll
        for (int mi = 0; mi < 4; mi++) {
            const int mbase = m0 + wm + mi * 16 + crow;
            #pragma unroll
            for (int r = 0; r < 4; r++)
                C[(size_t)(mbase + r) * OUTF + n] = acc[mi][ni][r] + bv;
        }
    }
}

// ---------------------------------------------------------------------------
extern "C" void kernel_launch(void* const* d_in, const int* in_sizes, int n_in,
                              void* d_out, int out_size, void* d_ws, size_t ws_size,
                              hipStream_t stream) {
    (void)in_sizes; (void)n_in; (void)out_size; (void)ws_size;
    const float* x     = (const float*)d_in[0];
    const float* theta = (const float*)d_in[1];
    const float* W0    = (const float*)d_in[2];
    const float* bias  = (const float*)d_in[3];
    const float* BB    = (const float*)d_in[4];
    const float* GG    = (const float*)d_in[5];
    const int*   Pi    = (const int*)d_in[6];      // int64 inputs arrive as int32
    float* out = (float*)d_out;

    char* ws = (char*)d_ws;
    ushort* XB   = (ushort*)ws;                      // 16384*768 bf16 = 25165824 B
    float*  T    = (float*)(ws + 25165824);          // LL f32 = 4194304 B
    ushort* WB   = (ushort*)(ws + 29360128);         // 1024*768 bf16 = 1572864 B
    float*  R01  = (float*)(ws + 30932992);          // 2048 f32
    float*  S    = (float*)(ws + 30941184);          // 1 f32
    float*  PART = (float*)(ws + 30941248);          // 256 f32 partials

    k1_sumsq <<<256, 256, 0, stream>>>(GG, PART);
    k0_fwht2 <<<1,   256, 0, stream>>>(BB, theta, PART, R01, S);
    k3_gather_fwht_lo<<<1024, 256, 0, stream>>>(Pi, GG, R01, T);
    k4_fwht_hi<<<128, 256, 0, stream>>>(T);
    k5_weff  <<<DD/1024, 256, 0, stream>>>(T, W0, S, WB);
    k6_xcast <<<(MROWS*INF)/1024, 256, 0, stream>>>(x, XB);
    k7_gemm  <<<dim3(OUTF/BN, MROWS/BM), 256, 0, stream>>>(XB, WB, bias, out);
}